// Round 2
// baseline (690.010 us; speedup 1.0000x reference)
//
#include <hip/hip_runtime.h>
#include <hip/hip_bf16.h>

typedef __hip_bfloat16 bf16;
typedef __attribute__((ext_vector_type(8))) short bf16x8;   // 8 bf16 = 4 VGPRs
typedef __attribute__((ext_vector_type(4))) float f32x4;

constexpr int DD = 128;     // feature dim
constexpr int NAC = 8192;   // actors
constexpr int NND = 65536;  // nodes
constexpr int NEG = 262144; // edges
constexpr int AP = 136;     // Abuf pitch (bf16): 68 dwords === 4 mod 32 -> 2-way aliasing (free per m136)
constexpr float GN_EPS = 1e-5f;

#define DEVINL __device__ __attribute__((always_inline)) static inline

// ---- one K=128 GEMM pass, B-fragments straight from global (L1/L2-hot weights).
//      C[32 rows x 128 ch] += A[32x128] * W[128x128]^T, per wave, zero barriers. ----
DEVINL void gemm_pass_g(const bf16* __restrict__ Wg, int wstride, int koff,
                        const bf16* Aw, f32x4 (&acc)[2][8], int quad, int l16)
{
    const bf16* Wl = Wg + (size_t)l16 * wstride + koff + quad * 8;
    #pragma unroll
    for (int kk = 0; kk < 128; kk += 32) {
        bf16x8 a0 = *(const bf16x8*)(Aw + l16 * AP + kk + quad * 8);
        bf16x8 a1 = *(const bf16x8*)(Aw + (16 + l16) * AP + kk + quad * 8);
        #pragma unroll
        for (int nt = 0; nt < 8; nt++) {
            bf16x8 b = *(const bf16x8*)(Wl + (size_t)nt * 16 * wstride + kk);
            acc[0][nt] = __builtin_amdgcn_mfma_f32_16x16x32_bf16(a0, b, acc[0][nt], 0, 0, 0);
            acc[1][nt] = __builtin_amdgcn_mfma_f32_16x16x32_bf16(a1, b, acc[1][nt], 0, 0, 0);
        }
    }
}

DEVINL void zero_acc(f32x4 (&acc)[2][8])
{
    #pragma unroll
    for (int i = 0; i < 2; i++)
        #pragma unroll
        for (int j = 0; j < 8; j++)
            acc[i][j] = f32x4{0.f, 0.f, 0.f, 0.f};
}

// ---- in-register GroupNorm(1 group, 128 ch) + ReLU -> wave-private Abuf (bf16) ----
DEVINL void gn_relu_to_lds(f32x4 (&acc)[2][8], const float* __restrict__ g,
                           const float* __restrict__ b, bf16* Aw, int quad, int l16)
{
    float gv[8], bv[8];
    #pragma unroll
    for (int nt = 0; nt < 8; nt++) { gv[nt] = g[nt * 16 + l16]; bv[nt] = b[nt * 16 + l16]; }
    #pragma unroll
    for (int mt = 0; mt < 2; mt++) {
        #pragma unroll
        for (int r = 0; r < 4; r++) {
            float s1 = 0.f, s2 = 0.f;
            #pragma unroll
            for (int nt = 0; nt < 8; nt++) { float v = acc[mt][nt][r]; s1 += v; s2 += v * v; }
            #pragma unroll
            for (int m = 1; m < 16; m <<= 1) { s1 += __shfl_xor(s1, m, 64); s2 += __shfl_xor(s2, m, 64); }
            float mean = s1 * (1.f / 128.f);
            float sc = rsqrtf(s2 * (1.f / 128.f) - mean * mean + GN_EPS);
            int row = mt * 16 + quad * 4 + r;
            #pragma unroll
            for (int nt = 0; nt < 8; nt++) {
                float y = (acc[mt][nt][r] - mean) * sc * gv[nt] + bv[nt];
                Aw[row * AP + nt * 16 + l16] = __float2bfloat16(fmaxf(y, 0.f));
            }
        }
    }
}

// ---- convert all 6 weight tensors (both blocks) fp32 -> bf16, concatenated ----
__global__ void conv_w_kernel(const float* __restrict__ d1, const float* __restrict__ qw,
                              const float* __restrict__ c0, const float* __restrict__ c1,
                              const float* __restrict__ ag, const float* __restrict__ li,
                              bf16* __restrict__ dst)
{
    int i4 = (blockIdx.x * blockDim.x + threadIdx.x) * 4;  // 262144 elems total
    const float* src; int off;
    if      (i4 < 32768)  { src = d1; off = 0; }
    else if (i4 < 65536)  { src = qw; off = 32768; }
    else if (i4 < 163840) { src = c0; off = 65536; }
    else if (i4 < 196608) { src = c1; off = 163840; }
    else if (i4 < 229376) { src = ag; off = 196608; }
    else                  { src = li; off = 229376; }
    float4 v = *(const float4*)(src + (i4 - off));
    dst[i4 + 0] = __float2bfloat16(v.x);
    dst[i4 + 1] = __float2bfloat16(v.y);
    dst[i4 + 2] = __float2bfloat16(v.z);
    dst[i4 + 3] = __float2bfloat16(v.w);
}

// ---- per-node precompute: nc = nodes @ Wc^T (ctx0 cols 256:384), bf16 out ----
__global__ __launch_bounds__(256, 3) void nodec_kernel(
    const float* __restrict__ nodes, const bf16* __restrict__ c0b, bf16* __restrict__ nc)
{
    __shared__ __align__(16) bf16 Abuf[128 * AP];
    int tid = threadIdx.x, wid = tid >> 6, lane = tid & 63, quad = lane >> 4, l16 = lane & 15;
    int r0 = blockIdx.x * 128 + wid * 32;
    bf16* Aw = Abuf + wid * 32 * AP;
    for (int rr = 0; rr < 32; rr++) {
        float2 v = ((const float2*)(nodes + (size_t)(r0 + rr) * DD))[lane];
        __hip_bfloat162 p; p.x = __float2bfloat16(v.x); p.y = __float2bfloat16(v.y);
        *(__hip_bfloat162*)(Aw + rr * AP + lane * 2) = p;
    }
    f32x4 acc[2][8]; zero_acc(acc);
    gemm_pass_g(c0b, 384, 256, Aw, acc, quad, l16);
    #pragma unroll
    for (int mt = 0; mt < 2; mt++)
        #pragma unroll
        for (int r = 0; r < 4; r++) {
            int row = r0 + mt * 16 + quad * 4 + r;
            #pragma unroll
            for (int nt = 0; nt < 8; nt++)
                nc[(size_t)row * DD + nt * 16 + l16] = __float2bfloat16(acc[mt][nt][r]);
        }
}

// ---- per-actor precompute: A_acc = actors @ agt^T (fp32 scatter base);
//      q = relu(GN(actors @ query^T)); qc = q @ Wq^T (ctx0 cols 128:256), bf16 out ----
__global__ __launch_bounds__(256, 3) void prep_kernel(
    const float* __restrict__ actors_in,
    const bf16* __restrict__ agb, const bf16* __restrict__ qwb,
    const float* __restrict__ qg, const float* __restrict__ qb,
    const bf16* __restrict__ c0b,
    bf16* __restrict__ qc, float* __restrict__ A_acc)
{
    __shared__ __align__(16) bf16 Abuf[128 * AP];
    int tid = threadIdx.x, wid = tid >> 6, lane = tid & 63, quad = lane >> 4, l16 = lane & 15;
    int r0 = blockIdx.x * 128 + wid * 32;
    bf16* Aw = Abuf + wid * 32 * AP;
    for (int rr = 0; rr < 32; rr++) {
        float2 v = ((const float2*)(actors_in + (size_t)(r0 + rr) * DD))[lane];
        __hip_bfloat162 p; p.x = __float2bfloat16(v.x); p.y = __float2bfloat16(v.y);
        *(__hip_bfloat162*)(Aw + rr * AP + lane * 2) = p;
    }
    f32x4 acc[2][8];
    // agt (reads actors from Aw)
    zero_acc(acc);
    gemm_pass_g(agb, 128, 0, Aw, acc, quad, l16);
    #pragma unroll
    for (int mt = 0; mt < 2; mt++)
        #pragma unroll
        for (int r = 0; r < 4; r++) {
            int row = r0 + mt * 16 + quad * 4 + r;
            #pragma unroll
            for (int nt = 0; nt < 8; nt++)
                A_acc[(size_t)row * DD + nt * 16 + l16] = acc[mt][nt][r];
        }
    // query -> GN+relu -> Aw (overwrite own rows)
    zero_acc(acc);
    gemm_pass_g(qwb, 128, 0, Aw, acc, quad, l16);
    gn_relu_to_lds(acc, qg, qb, Aw, quad, l16);
    // qc = q @ Wq^T
    zero_acc(acc);
    gemm_pass_g(c0b, 384, 128, Aw, acc, quad, l16);
    #pragma unroll
    for (int mt = 0; mt < 2; mt++)
        #pragma unroll
        for (int r = 0; r < 4; r++) {
            int row = r0 + mt * 16 + quad * 4 + r;
            #pragma unroll
            for (int nt = 0; nt < 8; nt++)
                qc[(size_t)row * DD + nt * 16 + l16] = __float2bfloat16(acc[mt][nt][r]);
        }
}

// ---- fused edge pipeline: dist MLP -> ctx0 -> ctx1 -> atomic scatter. Zero barriers. ----
__global__ __launch_bounds__(256, 3) void edge_kernel(
    const float* __restrict__ actor_ctrs, const float* __restrict__ node_ctrs,
    const int* __restrict__ hi, const int* __restrict__ wi,
    const float* __restrict__ d0W, const float* __restrict__ d0b,
    const bf16* __restrict__ d1w, const float* __restrict__ d1g, const float* __restrict__ d1bb,
    const bf16* __restrict__ qc, const bf16* __restrict__ nc,
    const bf16* __restrict__ c0w, const float* __restrict__ c0g, const float* __restrict__ c0bb,
    const bf16* __restrict__ c1w,
    float* __restrict__ A_acc)
{
    __shared__ __align__(16) bf16 Abuf[128 * AP];
    __shared__ float2 dxy[4][32];
    __shared__ int hbuf[4][32];
    __shared__ int wbuf[4][32];
    int tid = threadIdx.x, wid = tid >> 6, lane = tid & 63, quad = lane >> 4, l16 = lane & 15;
    int e0 = blockIdx.x * 128 + wid * 32;
    bf16* Aw = Abuf + wid * 32 * AP;

    // stage0a: parallel edge gathers (lanes 0..31 load one edge each), wave-private LDS
    if (lane < 32) {
        int e = e0 + lane;
        int h = hi[e], w = wi[e];
        hbuf[wid][lane] = h; wbuf[wid][lane] = w;
        float2 a2 = ((const float2*)actor_ctrs)[h];
        float2 n2 = ((const float2*)node_ctrs)[w];
        dxy[wid][lane] = float2{a2.x - n2.x, a2.y - n2.y};
    }
    // stage0b: h0 = relu(disp @ dist0^T + b0) -> Aw (each lane: 2 channels x 32 rows)
    {
        int ch = lane * 2;
        float w00 = d0W[ch * 2], w01 = d0W[ch * 2 + 1], bb0 = d0b[ch];
        float w10 = d0W[ch * 2 + 2], w11 = d0W[ch * 2 + 3], bb1 = d0b[ch + 1];
        #pragma unroll
        for (int rr = 0; rr < 32; rr++) {
            float2 d = dxy[wid][rr];   // LDS broadcast; same-wave RAW ordered by waitcnt
            float y0 = fmaxf(d.x * w00 + d.y * w01 + bb0, 0.f);
            float y1 = fmaxf(d.x * w10 + d.y * w11 + bb1, 0.f);
            __hip_bfloat162 p; p.x = __float2bfloat16(y0); p.y = __float2bfloat16(y1);
            *(__hip_bfloat162*)(Aw + rr * AP + ch) = p;
        }
    }
    f32x4 acc[2][8];

    // dist1: d = relu(GN(h0 @ dist1^T))
    zero_acc(acc);
    gemm_pass_g(d1w, 128, 0, Aw, acc, quad, l16);
    gn_relu_to_lds(acc, d1g, d1bb, Aw, quad, l16);

    // ctx0: acc init = qc[hi] + nc[wi] (indices from LDS), then += d @ Wd^T (cols 0:128)
    #pragma unroll
    for (int mt = 0; mt < 2; mt++)
        #pragma unroll
        for (int r = 0; r < 4; r++) {
            int el = mt * 16 + quad * 4 + r;
            const bf16* rq = qc + (size_t)hbuf[wid][el] * DD;
            const bf16* rn = nc + (size_t)wbuf[wid][el] * DD;
            #pragma unroll
            for (int nt = 0; nt < 8; nt++) {
                int ch = nt * 16 + l16;
                acc[mt][nt][r] = __bfloat162float(rq[ch]) + __bfloat162float(rn[ch]);
            }
        }
    gemm_pass_g(c0w, 384, 0, Aw, acc, quad, l16);
    gn_relu_to_lds(acc, c0g, c0bb, Aw, quad, l16);

    // ctx1 (linear) + atomic scatter into A_acc[hi]
    zero_acc(acc);
    gemm_pass_g(c1w, 128, 0, Aw, acc, quad, l16);
    #pragma unroll
    for (int mt = 0; mt < 2; mt++)
        #pragma unroll
        for (int r = 0; r < 4; r++) {
            int el = mt * 16 + quad * 4 + r;
            float* dst = A_acc + (size_t)hbuf[wid][el] * DD + l16;
            #pragma unroll
            for (int nt = 0; nt < 8; nt++)
                atomicAdd(dst + nt * 16, acc[mt][nt][r]);
        }
}

// ---- post: a=relu(GN(A_acc)); t=GN(a @ lin^T); out=relu(t + res) ----
__global__ __launch_bounds__(256, 3) void post_kernel(
    const float* __restrict__ A_acc,
    const float* __restrict__ ng, const float* __restrict__ nb,
    const bf16* __restrict__ liw, const float* __restrict__ lg, const float* __restrict__ lb,
    const float* __restrict__ resid, float* __restrict__ outp)
{
    __shared__ __align__(16) bf16 Abuf[128 * AP];
    int tid = threadIdx.x, wid = tid >> 6, lane = tid & 63, quad = lane >> 4, l16 = lane & 15;
    int r0 = blockIdx.x * 128 + wid * 32;
    bf16* Aw = Abuf + wid * 32 * AP;

    float2 g2 = ((const float2*)ng)[lane];
    float2 b2 = ((const float2*)nb)[lane];
    for (int rr = 0; rr < 32; rr++) {
        float2 x = ((const float2*)(A_acc + (size_t)(r0 + rr) * DD))[lane];
        float s1 = x.x + x.y, s2 = x.x * x.x + x.y * x.y;
        #pragma unroll
        for (int m = 1; m < 64; m <<= 1) { s1 += __shfl_xor(s1, m, 64); s2 += __shfl_xor(s2, m, 64); }
        float mean = s1 * (1.f / 128.f);
        float sc = rsqrtf(s2 * (1.f / 128.f) - mean * mean + GN_EPS);
        float y0 = fmaxf((x.x - mean) * sc * g2.x + b2.x, 0.f);
        float y1 = fmaxf((x.y - mean) * sc * g2.y + b2.y, 0.f);
        __hip_bfloat162 p; p.x = __float2bfloat16(y0); p.y = __float2bfloat16(y1);
        *(__hip_bfloat162*)(Aw + rr * AP + lane * 2) = p;
    }
    f32x4 acc[2][8]; zero_acc(acc);
    gemm_pass_g(liw, 128, 0, Aw, acc, quad, l16);

    float gv[8], bv[8];
    #pragma unroll
    for (int nt = 0; nt < 8; nt++) { gv[nt] = lg[nt * 16 + l16]; bv[nt] = lb[nt * 16 + l16]; }
    #pragma unroll
    for (int mt = 0; mt < 2; mt++)
        #pragma unroll
        for (int r = 0; r < 4; r++) {
            float s1 = 0.f, s2 = 0.f;
            #pragma unroll
            for (int nt = 0; nt < 8; nt++) { float v = acc[mt][nt][r]; s1 += v; s2 += v * v; }
            #pragma unroll
            for (int m = 1; m < 16; m <<= 1) { s1 += __shfl_xor(s1, m, 64); s2 += __shfl_xor(s2, m, 64); }
            float mean = s1 * (1.f / 128.f);
            float sc = rsqrtf(s2 * (1.f / 128.f) - mean * mean + GN_EPS);
            int row = r0 + mt * 16 + quad * 4 + r;
            #pragma unroll
            for (int nt = 0; nt < 8; nt++) {
                float y = (acc[mt][nt][r] - mean) * sc * gv[nt] + bv[nt];  // act=False before residual
                size_t o = (size_t)row * DD + nt * 16 + l16;
                outp[o] = fmaxf(y + resid[o], 0.f);
            }
        }
}

extern "C" void kernel_launch(void* const* d_in, const int* in_sizes, int n_in,
                              void* d_out, int out_size, void* d_ws, size_t ws_size,
                              hipStream_t stream)
{
    const float* actors     = (const float*)d_in[0];
    const float* nodes      = (const float*)d_in[1];
    const float* actor_ctrs = (const float*)d_in[2];
    const float* node_ctrs  = (const float*)d_in[3];
    const int*   hi         = (const int*)d_in[4];
    const int*   wi         = (const int*)d_in[5];
    const float* dist0_W    = (const float*)d_in[6];
    const float* dist0_b    = (const float*)d_in[7];
    const float* dist1_W    = (const float*)d_in[8];
    const float* dist1_g    = (const float*)d_in[9];
    const float* dist1_b    = (const float*)d_in[10];
    const float* query_W    = (const float*)d_in[11];
    const float* query_g    = (const float*)d_in[12];
    const float* query_b    = (const float*)d_in[13];
    const float* ctx0_W     = (const float*)d_in[14];
    const float* ctx0_g     = (const float*)d_in[15];
    const float* ctx0_b     = (const float*)d_in[16];
    const float* ctx1_W     = (const float*)d_in[17];
    const float* agt_W      = (const float*)d_in[18];
    const float* norm_g     = (const float*)d_in[19];
    const float* norm_b     = (const float*)d_in[20];
    const float* lin_W      = (const float*)d_in[21];
    const float* lin_g      = (const float*)d_in[22];
    const float* lin_b      = (const float*)d_in[23];

    // workspace layout (26.7 MB)
    char* ws = (char*)d_ws;
    bf16*  Wbf        = (bf16*)ws;                                  // 512 KB
    float* A_acc      = (float*)(ws + 524288);                      // 4 MB
    float* actors_mid = (float*)(ws + 524288 + 4194304);            // 4 MB
    bf16*  qc_bf      = (bf16*)(ws + 524288 + 8388608);             // 2 MB
    bf16*  nc_bf      = (bf16*)(ws + 524288 + 8388608 + 2097152);   // 16 MB

    conv_w_kernel<<<256, 256, 0, stream>>>(dist1_W, query_W, ctx0_W, ctx1_W, agt_W, lin_W, Wbf);

    for (int i = 0; i < 2; i++) {
        const bf16* d1b = Wbf + i * 16384;
        const bf16* qwb = Wbf + 32768 + i * 16384;
        const bf16* c0b = Wbf + 65536 + i * 49152;
        const bf16* c1b = Wbf + 163840 + i * 16384;
        const bf16* agb = Wbf + 196608 + i * 16384;
        const bf16* lib = Wbf + 229376 + i * 16384;
        const float* cur = i ? actors_mid : actors;
        float* nxt = i ? (float*)d_out : actors_mid;

        nodec_kernel<<<NND / 128, 256, 0, stream>>>(nodes, c0b, nc_bf);
        prep_kernel<<<NAC / 128, 256, 0, stream>>>(cur, agb, qwb,
            query_g + i * 128, query_b + i * 128, c0b, qc_bf, A_acc);
        edge_kernel<<<NEG / 128, 256, 0, stream>>>(actor_ctrs, node_ctrs, hi, wi,
            dist0_W + i * 256, dist0_b + i * 128,
            d1b, dist1_g + i * 128, dist1_b + i * 128,
            qc_bf, nc_bf, c0b, ctx0_g + i * 128, ctx0_b + i * 128, c1b, A_acc);
        post_kernel<<<NAC / 128, 256, 0, stream>>>(A_acc, norm_g + i * 128, norm_b + i * 128,
            lib, lin_g + i * 128, lin_b + i * 128, cur, nxt);
    }
}

// Round 3
// 496.152 us; speedup vs baseline: 1.3907x; 1.3907x over previous
//
#include <hip/hip_runtime.h>
#include <hip/hip_bf16.h>

typedef __hip_bfloat16 bf16;
typedef __attribute__((ext_vector_type(8))) short bf16x8;   // 8 bf16 = 4 VGPRs
typedef __attribute__((ext_vector_type(4))) float f32x4;

constexpr int DD = 128;     // feature dim
constexpr int NAC = 8192;   // actors
constexpr int NND = 65536;  // nodes
constexpr int NEG = 262144; // edges
constexpr int AP = 136;     // Abuf pitch (bf16): 16B-aligned rows; 68 dwords === 4 mod 32 -> 2-way (free)
constexpr int WP = 72;      // Wbuf pitch (bf16): 16B-aligned rows; 36 dwords === 4 mod 32 -> 2-way (free)
constexpr float GN_EPS = 1e-5f;

#define DEVINL __device__ __attribute__((always_inline)) static inline

// ---- cooperative load of a [128 rows x 64 k] weight slice into LDS (bf16) ----
DEVINL void load_w_slice(const bf16* __restrict__ Wg, int wstride, int koff,
                         bf16* Wbuf, int tid)
{
    int row  = tid >> 1;
    int half = tid & 1;
    const uint4* src = (const uint4*)(Wg + (size_t)row * wstride + koff + half * 32);
    uint4* dst = (uint4*)(Wbuf + row * WP + half * 32);
    dst[0] = src[0]; dst[1] = src[1]; dst[2] = src[2]; dst[3] = src[3];
}

// ---- one K=128 GEMM pass: C[32 rows x 128 ch] += A[32x128] * W[128x128]^T per wave ----
DEVINL void gemm_pass(const bf16* __restrict__ Wg, int wstride, int koff,
                      const bf16* Abuf, bf16* Wbuf,
                      f32x4 (&acc)[2][8], int eb, int quad, int l16, int tid)
{
    #pragma unroll
    for (int kh = 0; kh < 128; kh += 64) {
        __syncthreads();   // protect previous Wbuf readers
        load_w_slice(Wg, wstride, koff + kh, Wbuf, tid);
        __syncthreads();
        #pragma unroll
        for (int kk2 = 0; kk2 < 64; kk2 += 32) {
            int kk = kh + kk2;
            bf16x8 a0 = *(const bf16x8*)(Abuf + (eb + l16) * AP + kk + quad * 8);
            bf16x8 a1 = *(const bf16x8*)(Abuf + (eb + 16 + l16) * AP + kk + quad * 8);
            #pragma unroll
            for (int nt = 0; nt < 8; nt++) {
                bf16x8 b = *(const bf16x8*)(Wbuf + (nt * 16 + l16) * WP + kk2 + quad * 8);
                acc[0][nt] = __builtin_amdgcn_mfma_f32_16x16x32_bf16(a0, b, acc[0][nt], 0, 0, 0);
                acc[1][nt] = __builtin_amdgcn_mfma_f32_16x16x32_bf16(a1, b, acc[1][nt], 0, 0, 0);
            }
        }
    }
}

DEVINL void zero_acc(f32x4 (&acc)[2][8])
{
    #pragma unroll
    for (int i = 0; i < 2; i++)
        #pragma unroll
        for (int j = 0; j < 8; j++)
            acc[i][j] = f32x4{0.f, 0.f, 0.f, 0.f};
}

// ---- in-register GroupNorm(1 group over 128 ch) + ReLU, result -> Abuf (bf16) ----
DEVINL void gn_relu_to_lds(f32x4 (&acc)[2][8], const float* __restrict__ g,
                           const float* __restrict__ b, bf16* Abuf,
                           int eb, int quad, int l16)
{
    float gv[8], bv[8];
    #pragma unroll
    for (int nt = 0; nt < 8; nt++) { gv[nt] = g[nt * 16 + l16]; bv[nt] = b[nt * 16 + l16]; }
    #pragma unroll
    for (int mt = 0; mt < 2; mt++) {
        #pragma unroll
        for (int r = 0; r < 4; r++) {
            float s1 = 0.f, s2 = 0.f;
            #pragma unroll
            for (int nt = 0; nt < 8; nt++) { float v = acc[mt][nt][r]; s1 += v; s2 += v * v; }
            #pragma unroll
            for (int m = 1; m < 16; m <<= 1) { s1 += __shfl_xor(s1, m, 64); s2 += __shfl_xor(s2, m, 64); }
            float mean = s1 * (1.f / 128.f);
            float sc = rsqrtf(s2 * (1.f / 128.f) - mean * mean + GN_EPS);
            int row = eb + mt * 16 + quad * 4 + r;
            #pragma unroll
            for (int nt = 0; nt < 8; nt++) {
                float y = (acc[mt][nt][r] - mean) * sc * gv[nt] + bv[nt];
                Abuf[row * AP + nt * 16 + l16] = __float2bfloat16(fmaxf(y, 0.f));
            }
        }
    }
}

// ---- convert all 6 weight tensors (both blocks) fp32 -> bf16, concatenated ----
__global__ void conv_w_kernel(const float* __restrict__ d1, const float* __restrict__ qw,
                              const float* __restrict__ c0, const float* __restrict__ c1,
                              const float* __restrict__ ag, const float* __restrict__ li,
                              bf16* __restrict__ dst)
{
    int i4 = (blockIdx.x * blockDim.x + threadIdx.x) * 4;  // 262144 elems total
    const float* src; int off;
    if      (i4 < 32768)  { src = d1; off = 0; }
    else if (i4 < 65536)  { src = qw; off = 32768; }
    else if (i4 < 163840) { src = c0; off = 65536; }
    else if (i4 < 196608) { src = c1; off = 163840; }
    else if (i4 < 229376) { src = ag; off = 196608; }
    else                  { src = li; off = 229376; }
    float4 v = *(const float4*)(src + (i4 - off));
    dst[i4 + 0] = __float2bfloat16(v.x);
    dst[i4 + 1] = __float2bfloat16(v.y);
    dst[i4 + 2] = __float2bfloat16(v.z);
    dst[i4 + 3] = __float2bfloat16(v.w);
}

// =================== counting sort of edges by hi ===================
__global__ void zero_cnt_kernel(int* __restrict__ cnt)
{
    cnt[blockIdx.x * blockDim.x + threadIdx.x] = 0;   // 8192 ints
}

__global__ void hist_kernel(const int* __restrict__ hi, int* __restrict__ cnt)
{
    int e = blockIdx.x * blockDim.x + threadIdx.x;
    atomicAdd(&cnt[hi[e]], 1);
}

__global__ void scan_kernel(const int* __restrict__ cnt, int* __restrict__ cur)
{
    __shared__ int part[1024];
    int t = threadIdx.x;
    int local[8]; int s = 0;
    #pragma unroll
    for (int k = 0; k < 8; k++) { local[k] = cnt[t * 8 + k]; s += local[k]; }
    part[t] = s;
    __syncthreads();
    for (int d = 1; d < 1024; d <<= 1) {
        int v = (t >= d) ? part[t - d] : 0;
        __syncthreads();
        part[t] += v;
        __syncthreads();
    }
    int base = t ? part[t - 1] : 0;
    #pragma unroll
    for (int k = 0; k < 8; k++) { cur[t * 8 + k] = base; base += local[k]; }
}

// scatter sorted edge data: hi_s / wi_s / dxy_s at sorted positions
__global__ void scatter_kernel(const int* __restrict__ hi, const int* __restrict__ wi,
                               const float* __restrict__ actor_ctrs, const float* __restrict__ node_ctrs,
                               int* __restrict__ cur,
                               int* __restrict__ hi_s, int* __restrict__ wi_s,
                               float2* __restrict__ dxy_s)
{
    int e = blockIdx.x * blockDim.x + threadIdx.x;
    int h = hi[e], w = wi[e];
    int p = atomicAdd(&cur[h], 1);
    hi_s[p] = h; wi_s[p] = w;
    float2 a2 = ((const float2*)actor_ctrs)[h];
    float2 n2 = ((const float2*)node_ctrs)[w];
    dxy_s[p] = float2{a2.x - n2.x, a2.y - n2.y};
}

// ---- per-node precompute: nc = nodes @ Wc^T (ctx0 cols 256:384), bf16 out ----
__global__ __launch_bounds__(256, 3) void nodec_kernel(
    const float* __restrict__ nodes, const bf16* __restrict__ c0b, bf16* __restrict__ nc)
{
    __shared__ __align__(16) bf16 Abuf[128 * AP];
    __shared__ __align__(16) bf16 Wbuf[128 * WP];
    int tid = threadIdx.x, wid = tid >> 6, lane = tid & 63, quad = lane >> 4, l16 = lane & 15;
    int eb = wid * 32, r0 = blockIdx.x * 128;
    for (int rr = 0; rr < 32; rr++) {
        int row = r0 + eb + rr;
        float2 v = ((const float2*)(nodes + (size_t)row * DD))[lane];
        __hip_bfloat162 p; p.x = __float2bfloat16(v.x); p.y = __float2bfloat16(v.y);
        *(__hip_bfloat162*)(Abuf + (eb + rr) * AP + lane * 2) = p;
    }
    f32x4 acc[2][8]; zero_acc(acc);
    gemm_pass(c0b, 384, 256, Abuf, Wbuf, acc, eb, quad, l16, tid);
    #pragma unroll
    for (int mt = 0; mt < 2; mt++)
        #pragma unroll
        for (int r = 0; r < 4; r++) {
            int row = r0 + eb + mt * 16 + quad * 4 + r;
            #pragma unroll
            for (int nt = 0; nt < 8; nt++)
                nc[(size_t)row * DD + nt * 16 + l16] = __float2bfloat16(acc[mt][nt][r]);
        }
}

// ---- per-actor precompute: A_acc = actors @ agt^T; q = relu(GN(actors @ query^T));
//      qc = q @ Wq^T (ctx0 cols 128:256) ----
__global__ __launch_bounds__(256, 3) void prep_kernel(
    const float* __restrict__ actors_in,
    const bf16* __restrict__ agb, const bf16* __restrict__ qwb,
    const float* __restrict__ qg, const float* __restrict__ qb,
    const bf16* __restrict__ c0b,
    bf16* __restrict__ qc, float* __restrict__ A_acc)
{
    __shared__ __align__(16) bf16 Abuf[128 * AP];
    __shared__ __align__(16) bf16 Wbuf[128 * WP];
    int tid = threadIdx.x, wid = tid >> 6, lane = tid & 63, quad = lane >> 4, l16 = lane & 15;
    int eb = wid * 32, r0 = blockIdx.x * 128;
    for (int rr = 0; rr < 32; rr++) {
        int row = r0 + eb + rr;
        float2 v = ((const float2*)(actors_in + (size_t)row * DD))[lane];
        __hip_bfloat162 p; p.x = __float2bfloat16(v.x); p.y = __float2bfloat16(v.y);
        *(__hip_bfloat162*)(Abuf + (eb + rr) * AP + lane * 2) = p;
    }
    f32x4 acc[2][8];
    zero_acc(acc);
    gemm_pass(agb, 128, 0, Abuf, Wbuf, acc, eb, quad, l16, tid);
    #pragma unroll
    for (int mt = 0; mt < 2; mt++)
        #pragma unroll
        for (int r = 0; r < 4; r++) {
            int row = r0 + eb + mt * 16 + quad * 4 + r;
            #pragma unroll
            for (int nt = 0; nt < 8; nt++)
                A_acc[(size_t)row * DD + nt * 16 + l16] = acc[mt][nt][r];
        }
    zero_acc(acc);
    gemm_pass(qwb, 128, 0, Abuf, Wbuf, acc, eb, quad, l16, tid);
    gn_relu_to_lds(acc, qg, qb, Abuf, eb, quad, l16);
    zero_acc(acc);
    gemm_pass(c0b, 384, 128, Abuf, Wbuf, acc, eb, quad, l16, tid);
    #pragma unroll
    for (int mt = 0; mt < 2; mt++)
        #pragma unroll
        for (int r = 0; r < 4; r++) {
            int row = r0 + eb + mt * 16 + quad * 4 + r;
            #pragma unroll
            for (int nt = 0; nt < 8; nt++)
                qc[(size_t)row * DD + nt * 16 + l16] = __float2bfloat16(acc[mt][nt][r]);
        }
}

// ---- fused edge pipeline on SORTED edges: dist MLP -> ctx0 -> ctx1 -> run-reduced scatter ----
__global__ __launch_bounds__(256, 3) void edge_kernel(
    const int* __restrict__ hi_s, const int* __restrict__ wi_s, const float2* __restrict__ dxy_s,
    const float* __restrict__ d0W, const float* __restrict__ d0b,
    const bf16* __restrict__ d1w, const float* __restrict__ d1g, const float* __restrict__ d1bb,
    const bf16* __restrict__ qc, const bf16* __restrict__ nc,
    const bf16* __restrict__ c0w, const float* __restrict__ c0g, const float* __restrict__ c0bb,
    const bf16* __restrict__ c1w,
    float* __restrict__ A_acc)
{
    __shared__ __align__(16) bf16 Abuf[128 * AP];   // 34816 B
    __shared__ __align__(16) bf16 Wbuf[128 * WP];   // 18432 B
    __shared__ float2 dxy[4][32];                   // 1024 B  -> total 54272 B (3 blocks/CU)
    int tid = threadIdx.x, wid = tid >> 6, lane = tid & 63, quad = lane >> 4, l16 = lane & 15;
    int eb = wid * 32, e0 = blockIdx.x * 128 + eb;

    // stage0a: coalesced per-edge displacement loads (sorted order)
    if (lane < 32) dxy[wid][lane] = dxy_s[e0 + lane];
    // stage0b: h0 = relu(disp @ dist0^T + b0) -> Abuf (each lane: 2 channels x 32 rows)
    {
        int ch = lane * 2;
        float w00 = d0W[ch * 2], w01 = d0W[ch * 2 + 1], bb0 = d0b[ch];
        float w10 = d0W[ch * 2 + 2], w11 = d0W[ch * 2 + 3], bb1 = d0b[ch + 1];
        #pragma unroll
        for (int rr = 0; rr < 32; rr++) {
            float2 d = dxy[wid][rr];   // same-wave LDS RAW; compiler inserts lgkmcnt
            float y0 = fmaxf(d.x * w00 + d.y * w01 + bb0, 0.f);
            float y1 = fmaxf(d.x * w10 + d.y * w11 + bb1, 0.f);
            __hip_bfloat162 p; p.x = __float2bfloat16(y0); p.y = __float2bfloat16(y1);
            *(__hip_bfloat162*)(Abuf + (eb + rr) * AP + ch) = p;
        }
    }
    f32x4 acc[2][8];

    // dist1: d = relu(GN(h0 @ dist1^T))
    zero_acc(acc);
    gemm_pass(d1w, 128, 0, Abuf, Wbuf, acc, eb, quad, l16, tid);
    gn_relu_to_lds(acc, d1g, d1bb, Abuf, eb, quad, l16);

    // ctx0: acc init = qc[hi] + nc[wi] (hi runs sorted -> L1-hot), then += d @ Wd^T
    int hrows[2][4];
    #pragma unroll
    for (int mt = 0; mt < 2; mt++)
        #pragma unroll
        for (int r = 0; r < 4; r++) {
            int e = e0 + mt * 16 + quad * 4 + r;
            int h = hi_s[e]; hrows[mt][r] = h;
            const bf16* rq = qc + (size_t)h * DD;
            const bf16* rn = nc + (size_t)wi_s[e] * DD;
            #pragma unroll
            for (int nt = 0; nt < 8; nt++) {
                int ch = nt * 16 + l16;
                acc[mt][nt][r] = __bfloat162float(rq[ch]) + __bfloat162float(rn[ch]);
            }
        }
    gemm_pass(c0w, 384, 0, Abuf, Wbuf, acc, eb, quad, l16, tid);
    gn_relu_to_lds(acc, c0g, c0bb, Abuf, eb, quad, l16);

    // ctx1 (linear) + in-lane 4-row run reduction + atomic scatter into A_acc[hi]
    zero_acc(acc);
    gemm_pass(c1w, 128, 0, Abuf, Wbuf, acc, eb, quad, l16, tid);
    #pragma unroll
    for (int mt = 0; mt < 2; mt++) {
        float run[8];
        int curh = hrows[mt][0];
        #pragma unroll
        for (int nt = 0; nt < 8; nt++) run[nt] = acc[mt][nt][0];
        #pragma unroll
        for (int r = 1; r < 4; r++) {
            int hr = hrows[mt][r];
            if (hr == curh) {
                #pragma unroll
                for (int nt = 0; nt < 8; nt++) run[nt] += acc[mt][nt][r];
            } else {
                float* dst = A_acc + (size_t)curh * DD + l16;
                #pragma unroll
                for (int nt = 0; nt < 8; nt++) atomicAdd(dst + nt * 16, run[nt]);
                curh = hr;
                #pragma unroll
                for (int nt = 0; nt < 8; nt++) run[nt] = acc[mt][nt][r];
            }
        }
        float* dst = A_acc + (size_t)curh * DD + l16;
        #pragma unroll
        for (int nt = 0; nt < 8; nt++) atomicAdd(dst + nt * 16, run[nt]);
    }
}

// ---- post: a=relu(GN(A_acc)); t=GN(a @ lin^T); out=relu(t + res) ----
__global__ __launch_bounds__(256, 3) void post_kernel(
    const float* __restrict__ A_acc,
    const float* __restrict__ ng, const float* __restrict__ nb,
    const bf16* __restrict__ liw, const float* __restrict__ lg, const float* __restrict__ lb,
    const float* __restrict__ resid, float* __restrict__ outp)
{
    __shared__ __align__(16) bf16 Abuf[128 * AP];
    __shared__ __align__(16) bf16 Wbuf[128 * WP];
    int tid = threadIdx.x, wid = tid >> 6, lane = tid & 63, quad = lane >> 4, l16 = lane & 15;
    int eb = wid * 32, r0 = blockIdx.x * 128;

    float2 g2 = ((const float2*)ng)[lane];
    float2 b2 = ((const float2*)nb)[lane];
    for (int rr = 0; rr < 32; rr++) {
        int row = r0 + eb + rr;
        float2 x = ((const float2*)(A_acc + (size_t)row * DD))[lane];
        float s1 = x.x + x.y, s2 = x.x * x.x + x.y * x.y;
        #pragma unroll
        for (int m = 1; m < 64; m <<= 1) { s1 += __shfl_xor(s1, m, 64); s2 += __shfl_xor(s2, m, 64); }
        float mean = s1 * (1.f / 128.f);
        float sc = rsqrtf(s2 * (1.f / 128.f) - mean * mean + GN_EPS);
        float y0 = fmaxf((x.x - mean) * sc * g2.x + b2.x, 0.f);
        float y1 = fmaxf((x.y - mean) * sc * g2.y + b2.y, 0.f);
        __hip_bfloat162 p; p.x = __float2bfloat16(y0); p.y = __float2bfloat16(y1);
        *(__hip_bfloat162*)(Abuf + (eb + rr) * AP + lane * 2) = p;
    }
    f32x4 acc[2][8]; zero_acc(acc);
    gemm_pass(liw, 128, 0, Abuf, Wbuf, acc, eb, quad, l16, tid);

    float gv[8], bv[8];
    #pragma unroll
    for (int nt = 0; nt < 8; nt++) { gv[nt] = lg[nt * 16 + l16]; bv[nt] = lb[nt * 16 + l16]; }
    #pragma unroll
    for (int mt = 0; mt < 2; mt++)
        #pragma unroll
        for (int r = 0; r < 4; r++) {
            float s1 = 0.f, s2 = 0.f;
            #pragma unroll
            for (int nt = 0; nt < 8; nt++) { float v = acc[mt][nt][r]; s1 += v; s2 += v * v; }
            #pragma unroll
            for (int m = 1; m < 16; m <<= 1) { s1 += __shfl_xor(s1, m, 64); s2 += __shfl_xor(s2, m, 64); }
            float mean = s1 * (1.f / 128.f);
            float sc = rsqrtf(s2 * (1.f / 128.f) - mean * mean + GN_EPS);
            int row = r0 + eb + mt * 16 + quad * 4 + r;
            #pragma unroll
            for (int nt = 0; nt < 8; nt++) {
                float y = (acc[mt][nt][r] - mean) * sc * gv[nt] + bv[nt];  // act=False before residual
                size_t o = (size_t)row * DD + nt * 16 + l16;
                outp[o] = fmaxf(y + resid[o], 0.f);
            }
        }
}

extern "C" void kernel_launch(void* const* d_in, const int* in_sizes, int n_in,
                              void* d_out, int out_size, void* d_ws, size_t ws_size,
                              hipStream_t stream)
{
    const float* actors     = (const float*)d_in[0];
    const float* nodes      = (const float*)d_in[1];
    const float* actor_ctrs = (const float*)d_in[2];
    const float* node_ctrs  = (const float*)d_in[3];
    const int*   hi         = (const int*)d_in[4];
    const int*   wi         = (const int*)d_in[5];
    const float* dist0_W    = (const float*)d_in[6];
    const float* dist0_b    = (const float*)d_in[7];
    const float* dist1_W    = (const float*)d_in[8];
    const float* dist1_g    = (const float*)d_in[9];
    const float* dist1_b    = (const float*)d_in[10];
    const float* query_W    = (const float*)d_in[11];
    const float* query_g    = (const float*)d_in[12];
    const float* query_b    = (const float*)d_in[13];
    const float* ctx0_W     = (const float*)d_in[14];
    const float* ctx0_g     = (const float*)d_in[15];
    const float* ctx0_b     = (const float*)d_in[16];
    const float* ctx1_W     = (const float*)d_in[17];
    const float* agt_W      = (const float*)d_in[18];
    const float* norm_g     = (const float*)d_in[19];
    const float* norm_b     = (const float*)d_in[20];
    const float* lin_W      = (const float*)d_in[21];
    const float* lin_g      = (const float*)d_in[22];
    const float* lin_b      = (const float*)d_in[23];

    // workspace layout (~30.6 MB)
    char* ws = (char*)d_ws;
    size_t off = 0;
    bf16*  Wbf        = (bf16*)(ws + off);  off += 524288;      // 512 KB
    float* A_acc      = (float*)(ws + off); off += 4194304;     // 4 MB
    float* actors_mid = (float*)(ws + off); off += 4194304;     // 4 MB
    bf16*  qc_bf      = (bf16*)(ws + off);  off += 2097152;     // 2 MB
    bf16*  nc_bf      = (bf16*)(ws + off);  off += 16777216;    // 16 MB
    int*   cnt        = (int*)(ws + off);   off += 32768;       // 8192 ints
    int*   cur        = (int*)(ws + off);   off += 32768;       // 8192 ints
    int*   hi_s       = (int*)(ws + off);   off += 1048576;     // E ints
    int*   wi_s       = (int*)(ws + off);   off += 1048576;     // E ints
    float2* dxy_s     = (float2*)(ws + off); off += 2097152;    // E float2

    conv_w_kernel<<<256, 256, 0, stream>>>(dist1_W, query_W, ctx0_W, ctx1_W, agt_W, lin_W, Wbf);

    // counting sort by hi (shared by both Att blocks)
    zero_cnt_kernel<<<32, 256, 0, stream>>>(cnt);
    hist_kernel<<<NEG / 256, 256, 0, stream>>>(hi, cnt);
    scan_kernel<<<1, 1024, 0, stream>>>(cnt, cur);
    scatter_kernel<<<NEG / 256, 256, 0, stream>>>(hi, wi, actor_ctrs, node_ctrs,
                                                  cur, hi_s, wi_s, dxy_s);

    for (int i = 0; i < 2; i++) {
        const bf16* d1b = Wbf + i * 16384;
        const bf16* qwb = Wbf + 32768 + i * 16384;
        const bf16* c0b = Wbf + 65536 + i * 49152;
        const bf16* c1b = Wbf + 163840 + i * 16384;
        const bf16* agb = Wbf + 196608 + i * 16384;
        const bf16* lib = Wbf + 229376 + i * 16384;
        const float* curp = i ? actors_mid : actors;
        float* nxt = i ? (float*)d_out : actors_mid;

        nodec_kernel<<<NND / 128, 256, 0, stream>>>(nodes, c0b, nc_bf);
        prep_kernel<<<NAC / 128, 256, 0, stream>>>(curp, agb, qwb,
            query_g + i * 128, query_b + i * 128, c0b, qc_bf, A_acc);
        edge_kernel<<<NEG / 128, 256, 0, stream>>>(hi_s, wi_s, dxy_s,
            dist0_W + i * 256, dist0_b + i * 128,
            d1b, dist1_g + i * 128, dist1_b + i * 128,
            qc_bf, nc_bf, c0b, ctx0_g + i * 128, ctx0_b + i * 128, c1b, A_acc);
        post_kernel<<<NAC / 128, 256, 0, stream>>>(A_acc, norm_g + i * 128, norm_b + i * 128,
            lib, lin_g + i * 128, lin_b + i * 128, curp, nxt);
    }
}